// Round 5
// baseline (2768.286 us; speedup 1.0000x reference)
//
#include <hip/hip_runtime.h>
#include <cstddef>
#include <cstdint>

constexpr int kSeq = 512;
constexpr int kH   = 256;   // hidden per direction
constexpr int kG   = 1024;  // 4*kH (gates)
constexpr int kE   = 320;   // embed dim
constexpr int kLH  = 512;   // 2*kH
constexpr int kMLP = 512;
constexpr int kSlices = 4;  // working blocks per direction
constexpr int kSlice  = kH / kSlices;  // 64 h-elements per block

__device__ __forceinline__ float fexp2f(float x) {
  float r; asm("v_exp_f32 %0, %1" : "=v"(r) : "v"(x)); return r;
}
__device__ __forceinline__ float frcpf(float x) {
  float r; asm("v_rcp_f32 %0, %1" : "=v"(r) : "v"(x)); return r;
}
__device__ __forceinline__ float sigm(float x) {
  return frcpf(1.0f + fexp2f(-1.4426950408889634f * x));
}
__device__ __forceinline__ float tanh_(float x) {
  // tanh(x) = 1 - 2/(1+e^{2x}); e^{2x} = 2^(x*2*log2(e)). inf-safe at both ends.
  return 1.0f - 2.0f * frcpf(1.0f + fexp2f(2.8853900817779268f * x));
}

// ---------------- embedding gather ----------------
__global__ void embed_k(const int* __restrict__ wt, const int* __restrict__ pt,
                        const float* __restrict__ we, const float* __restrict__ pe,
                        float* __restrict__ X) {
  const int t = blockIdx.x;
  const int c = threadIdx.x;  // 0..319
  const int w = wt[t];
  const int p = pt[t];
  X[t * kE + c] = (c < 256) ? we[(size_t)w * 256 + c] : pe[p * 64 + (c - 256)];
}

// ---------------- generic f32 "NT" GEMM ----------------
template <int BM, int BN, int BK>
__global__ __launch_bounds__(256) void gemm_nt(
    const float* __restrict__ A, int lda,
    const float* __restrict__ B, int ldb,
    const float* __restrict__ b1, const float* __restrict__ b2, float scale,
    float* __restrict__ C, int csm, int csn, int K) {
  const int tid = threadIdx.x;
  const int m0 = blockIdx.y * BM;
  const int n0 = blockIdx.x * BN;
  __shared__ float As[BK][BM];
  __shared__ float Bs[BK][BN];
  const int lm = tid >> 2;
  const int lk = tid & 3;
  const int tx = tid & 15;
  const int ty = tid >> 4;
  float acc[4][4] = {};
  for (int k0 = 0; k0 < K; k0 += BK) {
    const float4 av = *(const float4*)(A + (size_t)(m0 + lm) * lda + k0 + lk * 4);
    const float4 bv = *(const float4*)(B + (size_t)(n0 + lm) * ldb + k0 + lk * 4);
    __syncthreads();
    As[lk * 4 + 0][lm] = av.x; As[lk * 4 + 1][lm] = av.y;
    As[lk * 4 + 2][lm] = av.z; As[lk * 4 + 3][lm] = av.w;
    Bs[lk * 4 + 0][lm] = bv.x; Bs[lk * 4 + 1][lm] = bv.y;
    Bs[lk * 4 + 2][lm] = bv.z; Bs[lk * 4 + 3][lm] = bv.w;
    __syncthreads();
#pragma unroll
    for (int kk = 0; kk < BK; ++kk) {
      const float4 a = *(const float4*)&As[kk][ty * 4];
      const float4 b = *(const float4*)&Bs[kk][tx * 4];
      acc[0][0] = fmaf(a.x, b.x, acc[0][0]);
      acc[0][1] = fmaf(a.x, b.y, acc[0][1]);
      acc[0][2] = fmaf(a.x, b.z, acc[0][2]);
      acc[0][3] = fmaf(a.x, b.w, acc[0][3]);
      acc[1][0] = fmaf(a.y, b.x, acc[1][0]);
      acc[1][1] = fmaf(a.y, b.y, acc[1][1]);
      acc[1][2] = fmaf(a.y, b.z, acc[1][2]);
      acc[1][3] = fmaf(a.y, b.w, acc[1][3]);
      acc[2][0] = fmaf(a.z, b.x, acc[2][0]);
      acc[2][1] = fmaf(a.z, b.y, acc[2][1]);
      acc[2][2] = fmaf(a.z, b.z, acc[2][2]);
      acc[2][3] = fmaf(a.z, b.w, acc[2][3]);
      acc[3][0] = fmaf(a.w, b.x, acc[3][0]);
      acc[3][1] = fmaf(a.w, b.y, acc[3][1]);
      acc[3][2] = fmaf(a.w, b.z, acc[3][2]);
      acc[3][3] = fmaf(a.w, b.w, acc[3][3]);
    }
  }
#pragma unroll
  for (int ii = 0; ii < 4; ++ii) {
#pragma unroll
    for (int jj = 0; jj < 4; ++jj) {
      const int m = m0 + ty * 4 + ii;
      const int n = n0 + tx * 4 + jj;
      float v = acc[ii][jj];
      if (b1) v += b1[n];
      if (b2) v += b2[n];
      C[(size_t)m * csm + (size_t)n * csn] = v * scale;
    }
  }
}

// ---------------- persistent multi-block LSTM scan, 2-sync overlapped ----------------
// Workers at blockIdx.x % 8 == 0 (logical id bb = bx>>3): if the HW maps
// consecutive blockIdx to different XCDs (round-robin), all 8 workers co-locate
// on one XCD, shortening the atomic coherence path; any other mapping is merely
// today's behavior (placement affects speed only, atomics carry correctness).
// Per step u: A) all 256 threads: full 256-col row dot of h(u-1) from LDS;
// S1; B) wave 0: gates -> atomic-store h FIRST, then LDS/out stores;
// waves 1-3: 2-deep pipelined poll of step-u remote words (overlaps gates and
// the store-visibility latency); S2. Two barriers per step.
__global__ __launch_bounds__(256, 1) void lstm_scan_x(
    const float* __restrict__ pre,   // (2, kSeq, kG) pregates
    const float* __restrict__ whh,   // (2, kG, kH)
    float* __restrict__ out,         // (kSeq, kLH); dir d -> cols [d*kH, d*kH+kH)
    float* __restrict__ comm)        // (2, kSeq, kH), pre-zeroed each launch
{
  if (blockIdx.x & 7) return;        // co-location dummies exit
  const int bb = blockIdx.x >> 3;    // 0..7
  const int d = bb >> 2;
  const int s = bb & 3;
  const int t = threadIdx.x;         // 0..255
  const int g = t >> 6;              // gate 0..3
  const int j = t & 63;              // element within slice
  const int grow = g * kH + s * kSlice + j;

  float4 w[64];                      // full Whh row: 256 f32
  {
    const float4* wp = (const float4*)(whh + ((size_t)d * kG + grow) * kH);
#pragma unroll
    for (int k = 0; k < 64; ++k) w[k] = wp[k];
  }

  __shared__ __align__(16) float h_sh[kH];
  __shared__ float gbuf[256];
  float* cm = comm + (size_t)d * kSeq * kH;
  float c = 0.0f;
  h_sh[t] = 0.0f;

  // poller mapping: threads 64..255 each own one remote word
  const int rid = t - 64;
  int rsl = rid >> 6;
  rsl += (rsl >= s) ? 1 : 0;
  const int rw = rid & 63;

  // prefetch pregate for u=0
  float pg_cur = pre[((size_t)d * kSeq + (d ? kSeq - 1 : 0)) * kG + grow];
  __syncthreads();

  for (int u = 0; u < kSeq; ++u) {
    const int ts = d ? (kSeq - 1 - u) : u;
    // ---- A: full-row dot over h(u-1) ----
    const float4* hp = (const float4*)h_sh;
    float a0 = 0.f, a1 = 0.f, a2 = 0.f, a3 = 0.f;
#pragma unroll
    for (int k = 0; k < 64; ++k) {
      const float4 h4 = hp[k];
      const float4 wk = w[k];
      a0 = fmaf(wk.x, h4.x, a0);
      a1 = fmaf(wk.y, h4.y, a1);
      a2 = fmaf(wk.z, h4.z, a2);
      a3 = fmaf(wk.w, h4.w, a3);
    }
    gbuf[t] = (a0 + a1) + (a2 + a3) + pg_cur;
    // prefetch pregate for u+1 (resolves during B phase / next A)
    {
      const int un = (u + 1 < kSeq) ? (u + 1) : u;
      const int tn = d ? (kSeq - 1 - un) : un;
      pg_cur = pre[((size_t)d * kSeq + tn) * kG + grow];
    }
    __syncthreads();  // S1: gbuf complete

    // ---- B: gates (wave 0) overlapped with remote polling (waves 1-3) ----
    if (t < kSlice) {
      const float gi = gbuf[t], gf = gbuf[64 + t], gg = gbuf[128 + t], go = gbuf[192 + t];
      const float iv = sigm(gi), fv = sigm(gf);
      const float gv = tanh_(gg), ov = sigm(go);
      c = fv * c + iv * gv;
      const float h = ov * tanh_(c);
      // visibility-critical store first
      __hip_atomic_store(&cm[(size_t)u * kH + s * kSlice + t], h + 2.0f,
                         __ATOMIC_RELAXED, __HIP_MEMORY_SCOPE_AGENT);
      h_sh[s * kSlice + t] = h;
      out[(size_t)ts * kLH + d * kH + s * kSlice + t] = h;
    } else {
      // 2-deep pipelined poll of one remote word of h(u)
      const float* src = &cm[(size_t)u * kH + rsl * kSlice + rw];
      float a = __hip_atomic_load(src, __ATOMIC_RELAXED, __HIP_MEMORY_SCOPE_AGENT);
      float b = __hip_atomic_load(src, __ATOMIC_RELAXED, __HIP_MEMORY_SCOPE_AGENT);
      while (a == 0.0f) {
        a = b;
        b = __hip_atomic_load(src, __ATOMIC_RELAXED, __HIP_MEMORY_SCOPE_AGENT);
      }
      h_sh[rsl * kSlice + rw] = a - 2.0f;
    }
    __syncthreads();  // S2: h(u) fully assembled in h_sh
  }
}

// ---------------- pair scorer ----------------
__global__ __launch_bounds__(512) void score_k(
    const float* __restrict__ Up, const float* __restrict__ VT,
    const float* __restrict__ wout, const float* __restrict__ bout,
    float* __restrict__ out) {
  const int i = blockIdx.x;
  const int j = threadIdx.x;
  __shared__ float u_sh[kMLP];
  __shared__ float w_sh[kMLP];
  u_sh[j] = Up[(size_t)i * kMLP + j];
  w_sh[j] = wout[j];
  __syncthreads();
  float acc = 0.0f;
#pragma unroll 4
  for (int m = 0; m < kMLP; ++m) {
    const float x = u_sh[m] + VT[(size_t)m * kSeq + j];  // pre-scaled by 2*log2e
    const float th = 1.0f - 2.0f * frcpf(1.0f + fexp2f(x));
    acc = fmaf(th, w_sh[m], acc);
  }
  const float s = acc + bout[0];
  out[(size_t)i * kSeq + j] = (j == i) ? 0.0f : s;
}

extern "C" void kernel_launch(void* const* d_in, const int* in_sizes, int n_in,
                              void* d_out, int out_size, void* d_ws, size_t ws_size,
                              hipStream_t stream) {
  const int*   wt   = (const int*)d_in[0];
  const int*   pt   = (const int*)d_in[1];
  const float* wemb = (const float*)d_in[2];
  const float* pemb = (const float*)d_in[3];
  const float* wih0 = (const float*)d_in[4];
  const float* whh0 = (const float*)d_in[5];
  const float* bih0 = (const float*)d_in[6];
  const float* bhh0 = (const float*)d_in[7];
  const float* wih1 = (const float*)d_in[8];
  const float* whh1 = (const float*)d_in[9];
  const float* bih1 = (const float*)d_in[10];
  const float* bhh1 = (const float*)d_in[11];
  const float* wlin = (const float*)d_in[12];
  const float* blin = (const float*)d_in[13];
  const float* wout = (const float*)d_in[14];
  const float* bout = (const float*)d_in[15];
  float* outp = (float*)d_out;

  float* ws   = (float*)d_ws;
  float* X    = ws;                      // 512*320
  float* PG0  = X + kSeq * kE;           // 2*512*1024
  float* X1   = PG0 + 2 * kSeq * kG;     // 512*512
  float* PG1  = X1 + kSeq * kLH;         // 2*512*1024
  float* LOUT = PG1 + 2 * kSeq * kG;     // 512*512
  float* U    = LOUT + kSeq * kLH;       // 512*512
  float* VT   = U + kSeq * kMLP;         // 512*512
  float* COMM0 = VT + kSeq * kMLP;       // 2*512*256
  float* COMM1 = COMM0 + 2 * kSeq * kH;  // 2*512*256

  const float SC = 2.8853900817779268f;  // 2*log2(e), folds tanh scaling

  // zero both layers' comm buffers (data-as-flag; fresh slot per step)
  hipMemsetAsync(COMM0, 0, 2 * 2 * kSeq * kH * sizeof(float), stream);

  embed_k<<<kSeq, kE, 0, stream>>>(wt, pt, wemb, pemb, X);

  for (int d = 0; d < 2; ++d) {
    gemm_nt<64, 64, 16><<<dim3(kG / 64, kSeq / 64), 256, 0, stream>>>(
        X, kE, wih0 + (size_t)d * kG * kE, kE,
        bih0 + d * kG, bhh0 + d * kG, 1.0f,
        PG0 + (size_t)d * kSeq * kG, kG, 1, kE);
  }
  lstm_scan_x<<<57, 256, 0, stream>>>(PG0, whh0, X1, COMM0);

  for (int d = 0; d < 2; ++d) {
    gemm_nt<64, 64, 16><<<dim3(kG / 64, kSeq / 64), 256, 0, stream>>>(
        X1, kLH, wih1 + (size_t)d * kG * kLH, kLH,
        bih1 + d * kG, bhh1 + d * kG, 1.0f,
        PG1 + (size_t)d * kSeq * kG, kG, 1, kLH);
  }
  lstm_scan_x<<<57, 256, 0, stream>>>(PG1, whh1, LOUT, COMM1);

  gemm_nt<64, 64, 16><<<dim3(kMLP / 64, kSeq / 64), 256, 0, stream>>>(
      LOUT, kLH, wlin, 2 * kLH, nullptr, nullptr, SC,
      U, kMLP, 1, kLH);
  gemm_nt<64, 64, 16><<<dim3(kMLP / 64, kSeq / 64), 256, 0, stream>>>(
      LOUT, kLH, wlin + kLH, 2 * kLH, blin, nullptr, SC,
      VT, 1, kSeq, kLH);

  score_k<<<kSeq, 512, 0, stream>>>(U, VT, wout, bout, outp);
}

// Round 6
// 2339.405 us; speedup vs baseline: 1.1833x; 1.1833x over previous
//
#include <hip/hip_runtime.h>
#include <cstddef>
#include <cstdint>

constexpr int kSeq = 512;
constexpr int kH   = 256;   // hidden per direction
constexpr int kG   = 1024;  // 4*kH (gates)
constexpr int kE   = 320;   // embed dim
constexpr int kLH  = 512;   // 2*kH
constexpr int kMLP = 512;
constexpr int kSlices = 4;  // blocks per direction
constexpr int kSlice  = kH / kSlices;  // 64 h-elements per block

__device__ __forceinline__ float fexp2f(float x) {
  float r; asm("v_exp_f32 %0, %1" : "=v"(r) : "v"(x)); return r;
}
__device__ __forceinline__ float frcpf(float x) {
  float r; asm("v_rcp_f32 %0, %1" : "=v"(r) : "v"(x)); return r;
}
__device__ __forceinline__ float sigm(float x) {
  return frcpf(1.0f + fexp2f(-1.4426950408889634f * x));
}
__device__ __forceinline__ float tanh_(float x) {
  // tanh(x) = 1 - 2/(1+e^{2x}); e^{2x} = 2^(x*2*log2(e)). inf-safe at both ends.
  return 1.0f - 2.0f * frcpf(1.0f + fexp2f(2.8853900817779268f * x));
}

// ---------------- embedding gather ----------------
__global__ void embed_k(const int* __restrict__ wt, const int* __restrict__ pt,
                        const float* __restrict__ we, const float* __restrict__ pe,
                        float* __restrict__ X) {
  const int t = blockIdx.x;
  const int c = threadIdx.x;  // 0..319
  const int w = wt[t];
  const int p = pt[t];
  X[t * kE + c] = (c < 256) ? we[(size_t)w * 256 + c] : pe[p * 64 + (c - 256)];
}

// ---------------- generic f32 "NT" GEMM ----------------
template <int BM, int BN, int BK>
__global__ __launch_bounds__(256) void gemm_nt(
    const float* __restrict__ A, int lda,
    const float* __restrict__ B, int ldb,
    const float* __restrict__ b1, const float* __restrict__ b2, float scale,
    float* __restrict__ C, int csm, int csn, int K) {
  const int tid = threadIdx.x;
  const int m0 = blockIdx.y * BM;
  const int n0 = blockIdx.x * BN;
  __shared__ float As[BK][BM];
  __shared__ float Bs[BK][BN];
  const int lm = tid >> 2;
  const int lk = tid & 3;
  const int tx = tid & 15;
  const int ty = tid >> 4;
  float acc[4][4] = {};
  for (int k0 = 0; k0 < K; k0 += BK) {
    const float4 av = *(const float4*)(A + (size_t)(m0 + lm) * lda + k0 + lk * 4);
    const float4 bv = *(const float4*)(B + (size_t)(n0 + lm) * ldb + k0 + lk * 4);
    __syncthreads();
    As[lk * 4 + 0][lm] = av.x; As[lk * 4 + 1][lm] = av.y;
    As[lk * 4 + 2][lm] = av.z; As[lk * 4 + 3][lm] = av.w;
    Bs[lk * 4 + 0][lm] = bv.x; Bs[lk * 4 + 1][lm] = bv.y;
    Bs[lk * 4 + 2][lm] = bv.z; Bs[lk * 4 + 3][lm] = bv.w;
    __syncthreads();
#pragma unroll
    for (int kk = 0; kk < BK; ++kk) {
      const float4 a = *(const float4*)&As[kk][ty * 4];
      const float4 b = *(const float4*)&Bs[kk][tx * 4];
      acc[0][0] = fmaf(a.x, b.x, acc[0][0]);
      acc[0][1] = fmaf(a.x, b.y, acc[0][1]);
      acc[0][2] = fmaf(a.x, b.z, acc[0][2]);
      acc[0][3] = fmaf(a.x, b.w, acc[0][3]);
      acc[1][0] = fmaf(a.y, b.x, acc[1][0]);
      acc[1][1] = fmaf(a.y, b.y, acc[1][1]);
      acc[1][2] = fmaf(a.y, b.z, acc[1][2]);
      acc[1][3] = fmaf(a.y, b.w, acc[1][3]);
      acc[2][0] = fmaf(a.z, b.x, acc[2][0]);
      acc[2][1] = fmaf(a.z, b.y, acc[2][1]);
      acc[2][2] = fmaf(a.z, b.z, acc[2][2]);
      acc[2][3] = fmaf(a.z, b.w, acc[2][3]);
      acc[3][0] = fmaf(a.w, b.x, acc[3][0]);
      acc[3][1] = fmaf(a.w, b.y, acc[3][1]);
      acc[3][2] = fmaf(a.w, b.z, acc[3][2]);
      acc[3][3] = fmaf(a.w, b.w, acc[3][3]);
    }
  }
#pragma unroll
  for (int ii = 0; ii < 4; ++ii) {
#pragma unroll
    for (int jj = 0; jj < 4; ++jj) {
      const int m = m0 + ty * 4 + ii;
      const int n = n0 + tx * 4 + jj;
      float v = acc[ii][jj];
      if (b1) v += b1[n];
      if (b2) v += b2[n];
      C[(size_t)m * csm + (size_t)n * csn] = v * scale;
    }
  }
}

// ---------------- persistent multi-block LSTM scan, latency-overlapped ----------------
// Round-4 structure (best so far) with LOW-CONTENTION polling:
//   - only wave 1 polls (3 words/lane, reload only pending), with s_sleep backoff
//   - waves 0,2,3 never touch the coherence point in the poll phase
// Row dot split by h-slice: own-slice partial in the poll window, remote partial
// after assembly. Sync = data-as-flag (fresh slot/step, pre-zeroed comm;
// producers atomic-store h+2.0 agent-scope).
__global__ __launch_bounds__(256, 1) void lstm_scan_ov(
    const float* __restrict__ pre,   // (2, kSeq, kG) pregates
    const float* __restrict__ whh,   // (2, kG, kH)
    float* __restrict__ out,         // (kSeq, kLH); dir d -> cols [d*kH, d*kH+kH)
    float* __restrict__ comm)        // (2, kSeq, kH), pre-zeroed each launch
{
  const int d = blockIdx.x >> 2;
  const int s = blockIdx.x & 3;
  const int t = threadIdx.x;       // 0..255
  const int g = t >> 6;            // gate 0..3
  const int j = t & 63;            // element within slice
  const int grow = g * kH + s * kSlice + j;

  // weights: own-slice block + 3 remote-slice blocks (row-major float4 view)
  float4 wown[16];
  float4 wrem[3][16];
  {
    const float4* wp = (const float4*)(whh + ((size_t)d * kG + grow) * kH);
#pragma unroll
    for (int k = 0; k < 16; ++k) wown[k] = wp[s * 16 + k];
#pragma unroll
    for (int rr = 0; rr < 3; ++rr) {
      const int ss = rr + (rr >= s ? 1 : 0);
#pragma unroll
      for (int k = 0; k < 16; ++k) wrem[rr][k] = wp[ss * 16 + k];
    }
  }

  __shared__ __align__(16) float h_sh[kH];
  __shared__ float gbuf[256];
  float* cm = comm + (size_t)d * kSeq * kH;
  float c = 0.0f;
  float pown = 0.0f;   // W_own . h_own(u-1); h(-1)=0
  if (t < kH) h_sh[t] = 0.0f;

  // single polling wave (wave 1): lane L polls one word in each remote slice
  const int L = t & 63;
  const int sl0 = (s + 1) & 3, sl1 = (s + 2) & 3, sl2 = (s + 3) & 3;

  // prefetch pregate for u=0
  float pg_cur = pre[((size_t)d * kSeq + (d ? kSeq - 1 : 0)) * kG + grow];
  __syncthreads();

  for (int u = 0; u < kSeq; ++u) {
    const int ts = d ? (kSeq - 1 - u) : u;
    // remote partial over h(u-1) (assembled in h_sh at end of prev iter)
    float a0 = 0.f, a1 = 0.f, a2 = 0.f, a3 = 0.f;
#pragma unroll
    for (int rr = 0; rr < 3; ++rr) {
      const int ss = rr + (rr >= s ? 1 : 0);
      const float4* hp = (const float4*)(h_sh + ss * kSlice);
#pragma unroll
      for (int k = 0; k < 16; ++k) {
        const float4 h4 = hp[k];
        const float4 wk = wrem[rr][k];
        a0 = fmaf(wk.x, h4.x, a0);
        a1 = fmaf(wk.y, h4.y, a1);
        a2 = fmaf(wk.z, h4.z, a2);
        a3 = fmaf(wk.w, h4.w, a3);
      }
    }
    gbuf[t] = (a0 + a1) + (a2 + a3) + pown + pg_cur;
    // prefetch pregate for u+1 (hides HBM latency under gates + poll)
    {
      const int un = (u + 1 < kSeq) ? (u + 1) : u;
      const int tn = d ? (kSeq - 1 - un) : un;
      pg_cur = pre[((size_t)d * kSeq + tn) * kG + grow];
    }
    __syncthreads();

    if (t < kSlice) {
      const float gi = gbuf[t], gf = gbuf[64 + t], gg = gbuf[128 + t], go = gbuf[192 + t];
      const float iv = sigm(gi), fv = sigm(gf);
      const float gv = tanh_(gg), ov = sigm(go);
      c = fv * c + iv * gv;
      const float h = ov * tanh_(c);
      // visibility-critical store first
      __hip_atomic_store(&cm[(size_t)u * kH + s * kSlice + t], h + 2.0f,
                         __ATOMIC_RELAXED, __HIP_MEMORY_SCOPE_AGENT);
      h_sh[s * kSlice + t] = h;
      out[(size_t)ts * kLH + d * kH + s * kSlice + t] = h;
    }
    __syncthreads();  // h_own(u) visible in h_sh

    if (t >= 64 && t < 128) {
      // wave 1: poll 3 remote words of h(u) with backoff; data IS the flag
      const float* base = &cm[(size_t)u * kH];
      const float* p0 = base + sl0 * kSlice + L;
      const float* p1 = base + sl1 * kSlice + L;
      const float* p2 = base + sl2 * kSlice + L;
      float v0 = 0.f, v1 = 0.f, v2 = 0.f;
      for (;;) {
        if (v0 == 0.f) v0 = __hip_atomic_load(p0, __ATOMIC_RELAXED, __HIP_MEMORY_SCOPE_AGENT);
        if (v1 == 0.f) v1 = __hip_atomic_load(p1, __ATOMIC_RELAXED, __HIP_MEMORY_SCOPE_AGENT);
        if (v2 == 0.f) v2 = __hip_atomic_load(p2, __ATOMIC_RELAXED, __HIP_MEMORY_SCOPE_AGENT);
        if (v0 != 0.f && v1 != 0.f && v2 != 0.f) break;
        __builtin_amdgcn_s_sleep(2);
      }
      h_sh[sl0 * kSlice + L] = v0 - 2.0f;
      h_sh[sl1 * kSlice + L] = v1 - 2.0f;
      h_sh[sl2 * kSlice + L] = v2 - 2.0f;
    }
    // own-slice partial for step u+1 (own region of h_sh stable; disjoint from
    // wave 1's remote writes). Overlaps the poll window for waves 0,2,3.
    {
      const float4* hp = (const float4*)(h_sh + s * kSlice);
      float b0 = 0.f, b1 = 0.f, b2 = 0.f, b3 = 0.f;
#pragma unroll
      for (int k = 0; k < 16; ++k) {
        const float4 h4 = hp[k];
        const float4 wk = wown[k];
        b0 = fmaf(wk.x, h4.x, b0);
        b1 = fmaf(wk.y, h4.y, b1);
        b2 = fmaf(wk.z, h4.z, b2);
        b3 = fmaf(wk.w, h4.w, b3);
      }
      pown = (b0 + b1) + (b2 + b3);
    }
    __syncthreads();  // h(u) fully assembled
  }
}

// ---------------- pair scorer ----------------
__global__ __launch_bounds__(512) void score_k(
    const float* __restrict__ Up, const float* __restrict__ VT,
    const float* __restrict__ wout, const float* __restrict__ bout,
    float* __restrict__ out) {
  const int i = blockIdx.x;
  const int j = threadIdx.x;
  __shared__ float u_sh[kMLP];
  __shared__ float w_sh[kMLP];
  u_sh[j] = Up[(size_t)i * kMLP + j];
  w_sh[j] = wout[j];
  __syncthreads();
  float acc = 0.0f;
#pragma unroll 4
  for (int m = 0; m < kMLP; ++m) {
    const float x = u_sh[m] + VT[(size_t)m * kSeq + j];  // pre-scaled by 2*log2e
    const float th = 1.0f - 2.0f * frcpf(1.0f + fexp2f(x));
    acc = fmaf(th, w_sh[m], acc);
  }
  const float s = acc + bout[0];
  out[(size_t)i * kSeq + j] = (j == i) ? 0.0f : s;
}

extern "C" void kernel_launch(void* const* d_in, const int* in_sizes, int n_in,
                              void* d_out, int out_size, void* d_ws, size_t ws_size,
                              hipStream_t stream) {
  const int*   wt   = (const int*)d_in[0];
  const int*   pt   = (const int*)d_in[1];
  const float* wemb = (const float*)d_in[2];
  const float* pemb = (const float*)d_in[3];
  const float* wih0 = (const float*)d_in[4];
  const float* whh0 = (const float*)d_in[5];
  const float* bih0 = (const float*)d_in[6];
  const float* bhh0 = (const float*)d_in[7];
  const float* wih1 = (const float*)d_in[8];
  const float* whh1 = (const float*)d_in[9];
  const float* bih1 = (const float*)d_in[10];
  const float* bhh1 = (const float*)d_in[11];
  const float* wlin = (const float*)d_in[12];
  const float* blin = (const float*)d_in[13];
  const float* wout = (const float*)d_in[14];
  const float* bout = (const float*)d_in[15];
  float* outp = (float*)d_out;

  float* ws   = (float*)d_ws;
  float* X    = ws;                      // 512*320
  float* PG0  = X + kSeq * kE;           // 2*512*1024
  float* X1   = PG0 + 2 * kSeq * kG;     // 512*512
  float* PG1  = X1 + kSeq * kLH;         // 2*512*1024
  float* LOUT = PG1 + 2 * kSeq * kG;     // 512*512
  float* U    = LOUT + kSeq * kLH;       // 512*512
  float* VT   = U + kSeq * kMLP;         // 512*512
  float* COMM0 = VT + kSeq * kMLP;       // 2*512*256
  float* COMM1 = COMM0 + 2 * kSeq * kH;  // 2*512*256

  const float SC = 2.8853900817779268f;  // 2*log2(e), folds tanh scaling

  // zero both layers' comm buffers (data-as-flag; fresh slot per step)
  hipMemsetAsync(COMM0, 0, 2 * 2 * kSeq * kH * sizeof(float), stream);

  embed_k<<<kSeq, kE, 0, stream>>>(wt, pt, wemb, pemb, X);

  for (int d = 0; d < 2; ++d) {
    gemm_nt<64, 64, 16><<<dim3(kG / 64, kSeq / 64), 256, 0, stream>>>(
        X, kE, wih0 + (size_t)d * kG * kE, kE,
        bih0 + d * kG, bhh0 + d * kG, 1.0f,
        PG0 + (size_t)d * kSeq * kG, kG, 1, kE);
  }
  lstm_scan_ov<<<2 * kSlices, 256, 0, stream>>>(PG0, whh0, X1, COMM0);

  for (int d = 0; d < 2; ++d) {
    gemm_nt<64, 64, 16><<<dim3(kG / 64, kSeq / 64), 256, 0, stream>>>(
        X1, kLH, wih1 + (size_t)d * kG * kLH, kLH,
        bih1 + d * kG, bhh1 + d * kG, 1.0f,
        PG1 + (size_t)d * kSeq * kG, kG, 1, kLH);
  }
  lstm_scan_ov<<<2 * kSlices, 256, 0, stream>>>(PG1, whh1, LOUT, COMM1);

  gemm_nt<64, 64, 16><<<dim3(kMLP / 64, kSeq / 64), 256, 0, stream>>>(
      LOUT, kLH, wlin, 2 * kLH, nullptr, nullptr, SC,
      U, kMLP, 1, kLH);
  gemm_nt<64, 64, 16><<<dim3(kMLP / 64, kSeq / 64), 256, 0, stream>>>(
      LOUT, kLH, wlin + kLH, 2 * kLH, blin, nullptr, SC,
      VT, 1, kSeq, kLH);

  score_k<<<kSeq, 512, 0, stream>>>(U, VT, wout, bout, outp);
}

// Round 7
// 2235.981 us; speedup vs baseline: 1.2381x; 1.0463x over previous
//
#include <hip/hip_runtime.h>
#include <cstddef>
#include <cstdint>

constexpr int kSeq = 512;
constexpr int kH   = 256;   // hidden per direction
constexpr int kG   = 1024;  // 4*kH (gates)
constexpr int kE   = 320;   // embed dim
constexpr int kLH  = 512;   // 2*kH
constexpr int kMLP = 512;

typedef _Float16 h2 __attribute__((ext_vector_type(2)));

__device__ __forceinline__ float fexp2f(float x) {
  float r; asm("v_exp_f32 %0, %1" : "=v"(r) : "v"(x)); return r;
}
__device__ __forceinline__ float frcpf(float x) {
  float r; asm("v_rcp_f32 %0, %1" : "=v"(r) : "v"(x)); return r;
}
__device__ __forceinline__ float sigm(float x) {
  return frcpf(1.0f + fexp2f(-1.4426950408889634f * x));
}
__device__ __forceinline__ float tanh_(float x) {
  // tanh(x) = 1 - 2/(1+e^{2x}); e^{2x} = 2^(x*2*log2(e)). inf-safe at both ends.
  return 1.0f - 2.0f * frcpf(1.0f + fexp2f(2.8853900817779268f * x));
}

__device__ __forceinline__ float fdot2(unsigned int w, unsigned int h, float c) {
#if __has_builtin(__builtin_amdgcn_fdot2)
  return __builtin_amdgcn_fdot2(__builtin_bit_cast(h2, w),
                                __builtin_bit_cast(h2, h), c, false);
#else
  const h2 wv = __builtin_bit_cast(h2, w);
  const h2 hv = __builtin_bit_cast(h2, h);
  return c + (float)wv.x * (float)hv.x + (float)wv.y * (float)hv.y;
#endif
}

__device__ __forceinline__ unsigned int packh2(float a, float b) {
  h2 v; v.x = (_Float16)a; v.y = (_Float16)b;
  return __builtin_bit_cast(unsigned int, v);
}

// ---------------- embedding gather ----------------
__global__ void embed_k(const int* __restrict__ wt, const int* __restrict__ pt,
                        const float* __restrict__ we, const float* __restrict__ pe,
                        float* __restrict__ X) {
  const int t = blockIdx.x;
  const int c = threadIdx.x;  // 0..319
  const int w = wt[t];
  const int p = pt[t];
  X[t * kE + c] = (c < 256) ? we[(size_t)w * 256 + c] : pe[p * 64 + (c - 256)];
}

// ---------------- generic f32 "NT" GEMM ----------------
template <int BM, int BN, int BK>
__global__ __launch_bounds__(256) void gemm_nt(
    const float* __restrict__ A, int lda,
    const float* __restrict__ B, int ldb,
    const float* __restrict__ b1, const float* __restrict__ b2, float scale,
    float* __restrict__ C, int csm, int csn, int K) {
  const int tid = threadIdx.x;
  const int m0 = blockIdx.y * BM;
  const int n0 = blockIdx.x * BN;
  __shared__ float As[BK][BM];
  __shared__ float Bs[BK][BN];
  const int lm = tid >> 2;
  const int lk = tid & 3;
  const int tx = tid & 15;
  const int ty = tid >> 4;
  float acc[4][4] = {};
  for (int k0 = 0; k0 < K; k0 += BK) {
    const float4 av = *(const float4*)(A + (size_t)(m0 + lm) * lda + k0 + lk * 4);
    const float4 bv = *(const float4*)(B + (size_t)(n0 + lm) * ldb + k0 + lk * 4);
    __syncthreads();
    As[lk * 4 + 0][lm] = av.x; As[lk * 4 + 1][lm] = av.y;
    As[lk * 4 + 2][lm] = av.z; As[lk * 4 + 3][lm] = av.w;
    Bs[lk * 4 + 0][lm] = bv.x; Bs[lk * 4 + 1][lm] = bv.y;
    Bs[lk * 4 + 2][lm] = bv.z; Bs[lk * 4 + 3][lm] = bv.w;
    __syncthreads();
#pragma unroll
    for (int kk = 0; kk < BK; ++kk) {
      const float4 a = *(const float4*)&As[kk][ty * 4];
      const float4 b = *(const float4*)&Bs[kk][tx * 4];
      acc[0][0] = fmaf(a.x, b.x, acc[0][0]);
      acc[0][1] = fmaf(a.x, b.y, acc[0][1]);
      acc[0][2] = fmaf(a.x, b.z, acc[0][2]);
      acc[0][3] = fmaf(a.x, b.w, acc[0][3]);
      acc[1][0] = fmaf(a.y, b.x, acc[1][0]);
      acc[1][1] = fmaf(a.y, b.y, acc[1][1]);
      acc[1][2] = fmaf(a.y, b.z, acc[1][2]);
      acc[1][3] = fmaf(a.y, b.w, acc[1][3]);
      acc[2][0] = fmaf(a.z, b.x, acc[2][0]);
      acc[2][1] = fmaf(a.z, b.y, acc[2][1]);
      acc[2][2] = fmaf(a.z, b.z, acc[2][2]);
      acc[2][3] = fmaf(a.z, b.w, acc[2][3]);
      acc[3][0] = fmaf(a.w, b.x, acc[3][0]);
      acc[3][1] = fmaf(a.w, b.y, acc[3][1]);
      acc[3][2] = fmaf(a.w, b.z, acc[3][2]);
      acc[3][3] = fmaf(a.w, b.w, acc[3][3]);
    }
  }
#pragma unroll
  for (int ii = 0; ii < 4; ++ii) {
#pragma unroll
    for (int jj = 0; jj < 4; ++jj) {
      const int m = m0 + ty * 4 + ii;
      const int n = n0 + tx * 4 + jj;
      float v = acc[ii][jj];
      if (b1) v += b1[n];
      if (b2) v += b2[n];
      C[(size_t)m * csm + (size_t)n * csn] = v * scale;
    }
  }
}

// ---------------- single-block-per-direction LSTM scan, f16 weights ----------------
// 2 blocks total (d = blockIdx.x), 1024 threads. Thread t owns gate row t.
// Whh row (256 cols) as f16: cols 0..191 in 96 VGPR uints, cols 192..255 in LDS
// (lane-contiguous uint4 layout, conflict-free). h broadcast as packed half2
// from LDS. Accumulation f32 (v_dot2_f32_f16). NO inter-block communication.
// Dynamic LDS: 128KB weights + 4KB gbuf + 512B hh = 135680 B.
__global__ __launch_bounds__(1024, 1) void lstm_scan_f16(
    const float* __restrict__ pre,   // (2, kSeq, kG) pregates
    const float* __restrict__ whh,   // (2, kG, kH) f32
    float* __restrict__ out) {       // (kSeq, kLH); dir d -> cols [d*kH, d*kH+kH)
  extern __shared__ __align__(16) char smem[];
  uint4*        wl4  = (uint4*)smem;                        // 8192 uint4 = 128KB
  float*        gbuf = (float*)(smem + 131072);             // 1024 f32 = 4KB
  unsigned int* hh   = (unsigned int*)(smem + 131072 + 4096);  // 128 uints = 512B

  const int d = blockIdx.x;
  const int t = threadIdx.x;   // 0..1023 == gate row

  // ---- prologue: convert this row's weights to f16 ----
  unsigned int wreg[96];       // cols 0..191
  {
    const float4* wp = (const float4*)(whh + ((size_t)d * kG + t) * kH);
#pragma unroll
    for (int k = 0; k < 48; ++k) {
      const float4 v = wp[k];
      wreg[2 * k]     = packh2(v.x, v.y);
      wreg[2 * k + 1] = packh2(v.z, v.w);
    }
#pragma unroll
    for (int k = 0; k < 8; ++k) {   // cols 192..255 -> LDS
      const float4 a = wp[48 + 2 * k];
      const float4 b = wp[48 + 2 * k + 1];
      uint4 q;
      q.x = packh2(a.x, a.y); q.y = packh2(a.z, a.w);
      q.z = packh2(b.x, b.y); q.w = packh2(b.z, b.w);
      wl4[k * 1024 + t] = q;
    }
  }
  if (t < 128) hh[t] = 0u;     // h(-1) = 0
  __syncthreads();

  float c = 0.0f;
  const uint4* hh4 = (const uint4*)hh;   // 32 chunks of 4 half2 (8 cols)

  for (int u = 0; u < kSeq; ++u) {
    const int ts = d ? (kSeq - 1 - u) : u;
    // issue pregate load early; resolves under the dot
    const float pg = pre[((size_t)d * kSeq + ts) * kG + t];

    float ac0 = 0.f, ac1 = 0.f, ac2 = 0.f, ac3 = 0.f;
#pragma unroll
    for (int k = 0; k < 24; ++k) {       // cols 0..191 from VGPR weights
      const uint4 hv = hh4[k];           // broadcast LDS read
      ac0 = fdot2(wreg[4 * k + 0], hv.x, ac0);
      ac1 = fdot2(wreg[4 * k + 1], hv.y, ac1);
      ac2 = fdot2(wreg[4 * k + 2], hv.z, ac2);
      ac3 = fdot2(wreg[4 * k + 3], hv.w, ac3);
    }
#pragma unroll
    for (int k = 0; k < 8; ++k) {        // cols 192..255 from LDS weights
      const uint4 wv = wl4[k * 1024 + t];
      const uint4 hv = hh4[24 + k];
      ac0 = fdot2(wv.x, hv.x, ac0);
      ac1 = fdot2(wv.y, hv.y, ac1);
      ac2 = fdot2(wv.z, hv.z, ac2);
      ac3 = fdot2(wv.w, hv.w, ac3);
    }
    gbuf[t] = (ac0 + ac1) + (ac2 + ac3) + pg;
    __syncthreads();   // S1: all gates ready

    if (t < kH) {
      const float gi = gbuf[t];
      const float gf = gbuf[kH + t];
      const float gg = gbuf[2 * kH + t];
      const float go = gbuf[3 * kH + t];
      const float iv = sigm(gi), fv = sigm(gf);
      const float gv = tanh_(gg), ov = sigm(go);
      c = fv * c + iv * gv;
      const float h = ov * tanh_(c);
      ((_Float16*)hh)[t] = (_Float16)h;   // quantized h for the recurrence
      out[(size_t)ts * kLH + d * kH + t] = h;  // full-precision h downstream
    }
    __syncthreads();   // S2: hh(u) assembled
  }
}

// ---------------- pair scorer ----------------
__global__ __launch_bounds__(512) void score_k(
    const float* __restrict__ Up, const float* __restrict__ VT,
    const float* __restrict__ wout, const float* __restrict__ bout,
    float* __restrict__ out) {
  const int i = blockIdx.x;
  const int j = threadIdx.x;
  __shared__ float u_sh[kMLP];
  __shared__ float w_sh[kMLP];
  u_sh[j] = Up[(size_t)i * kMLP + j];
  w_sh[j] = wout[j];
  __syncthreads();
  float acc = 0.0f;
#pragma unroll 4
  for (int m = 0; m < kMLP; ++m) {
    const float x = u_sh[m] + VT[(size_t)m * kSeq + j];  // pre-scaled by 2*log2e
    const float th = 1.0f - 2.0f * frcpf(1.0f + fexp2f(x));
    acc = fmaf(th, w_sh[m], acc);
  }
  const float s = acc + bout[0];
  out[(size_t)i * kSeq + j] = (j == i) ? 0.0f : s;
}

extern "C" void kernel_launch(void* const* d_in, const int* in_sizes, int n_in,
                              void* d_out, int out_size, void* d_ws, size_t ws_size,
                              hipStream_t stream) {
  const int*   wt   = (const int*)d_in[0];
  const int*   pt   = (const int*)d_in[1];
  const float* wemb = (const float*)d_in[2];
  const float* pemb = (const float*)d_in[3];
  const float* wih0 = (const float*)d_in[4];
  const float* whh0 = (const float*)d_in[5];
  const float* bih0 = (const float*)d_in[6];
  const float* bhh0 = (const float*)d_in[7];
  const float* wih1 = (const float*)d_in[8];
  const float* whh1 = (const float*)d_in[9];
  const float* bih1 = (const float*)d_in[10];
  const float* bhh1 = (const float*)d_in[11];
  const float* wlin = (const float*)d_in[12];
  const float* blin = (const float*)d_in[13];
  const float* wout = (const float*)d_in[14];
  const float* bout = (const float*)d_in[15];
  float* outp = (float*)d_out;

  float* ws   = (float*)d_ws;
  float* X    = ws;                      // 512*320
  float* PG0  = X + kSeq * kE;           // 2*512*1024
  float* X1   = PG0 + 2 * kSeq * kG;     // 512*512
  float* PG1  = X1 + kSeq * kLH;         // 2*512*1024
  float* LOUT = PG1 + 2 * kSeq * kG;     // 512*512
  float* U    = LOUT + kSeq * kLH;       // 512*512
  float* VT   = U + kSeq * kMLP;         // 512*512

  const float SC = 2.8853900817779268f;  // 2*log2(e), folds tanh scaling
  const int kScanLds = 131072 + 4096 + 512;  // weights + gbuf + hh

  hipFuncSetAttribute(reinterpret_cast<const void*>(lstm_scan_f16),
                      hipFuncAttributeMaxDynamicSharedMemorySize, kScanLds);

  embed_k<<<kSeq, kE, 0, stream>>>(wt, pt, wemb, pemb, X);

  for (int d = 0; d < 2; ++d) {
    gemm_nt<64, 64, 16><<<dim3(kG / 64, kSeq / 64), 256, 0, stream>>>(
        X, kE, wih0 + (size_t)d * kG * kE, kE,
        bih0 + d * kG, bhh0 + d * kG, 1.0f,
        PG0 + (size_t)d * kSeq * kG, kG, 1, kE);
  }
  lstm_scan_f16<<<2, 1024, kScanLds, stream>>>(PG0, whh0, X1);

  for (int d = 0; d < 2; ++d) {
    gemm_nt<64, 64, 16><<<dim3(kG / 64, kSeq / 64), 256, 0, stream>>>(
        X1, kLH, wih1 + (size_t)d * kG * kLH, kLH,
        bih1 + d * kG, bhh1 + d * kG, 1.0f,
        PG1 + (size_t)d * kSeq * kG, kG, 1, kLH);
  }
  lstm_scan_f16<<<2, 1024, kScanLds, stream>>>(PG1, whh1, LOUT);

  gemm_nt<64, 64, 16><<<dim3(kMLP / 64, kSeq / 64), 256, 0, stream>>>(
      LOUT, kLH, wlin, 2 * kLH, nullptr, nullptr, SC,
      U, kMLP, 1, kLH);
  gemm_nt<64, 64, 16><<<dim3(kMLP / 64, kSeq / 64), 256, 0, stream>>>(
      LOUT, kLH, wlin + kLH, 2 * kLH, blin, nullptr, SC,
      VT, 1, kSeq, kLH);

  score_k<<<kSeq, 512, 0, stream>>>(U, VT, wout, bout, outp);
}

// Round 8
// 1949.384 us; speedup vs baseline: 1.4201x; 1.1470x over previous
//
#include <hip/hip_runtime.h>
#include <cstddef>
#include <cstdint>

constexpr int kSeq = 512;
constexpr int kH   = 256;   // hidden per direction
constexpr int kG   = 1024;  // 4*kH (gates)
constexpr int kE   = 320;   // embed dim
constexpr int kLH  = 512;   // 2*kH
constexpr int kMLP = 512;

typedef _Float16 h2 __attribute__((ext_vector_type(2)));

__device__ __forceinline__ float fexp2f(float x) {
  float r; asm("v_exp_f32 %0, %1" : "=v"(r) : "v"(x)); return r;
}
__device__ __forceinline__ float frcpf(float x) {
  float r; asm("v_rcp_f32 %0, %1" : "=v"(r) : "v"(x)); return r;
}
__device__ __forceinline__ float sigm(float x) {
  return frcpf(1.0f + fexp2f(-1.4426950408889634f * x));
}
__device__ __forceinline__ float tanh_(float x) {
  // tanh(x) = 1 - 2/(1+e^{2x}); e^{2x} = 2^(x*2*log2(e)). inf-safe at both ends.
  return 1.0f - 2.0f * frcpf(1.0f + fexp2f(2.8853900817779268f * x));
}

__device__ __forceinline__ float fdot2(unsigned int w, unsigned int h, float c) {
#if __has_builtin(__builtin_amdgcn_fdot2)
  return __builtin_amdgcn_fdot2(__builtin_bit_cast(h2, w),
                                __builtin_bit_cast(h2, h), c, false);
#else
  const h2 wv = __builtin_bit_cast(h2, w);
  const h2 hv = __builtin_bit_cast(h2, h);
  return c + (float)wv.x * (float)hv.x + (float)wv.y * (float)hv.y;
#endif
}

__device__ __forceinline__ unsigned int packh2(float a, float b) {
  h2 v; v.x = (_Float16)a; v.y = (_Float16)b;
  return __builtin_bit_cast(unsigned int, v);
}

// ---------------- embedding gather ----------------
__global__ void embed_k(const int* __restrict__ wt, const int* __restrict__ pt,
                        const float* __restrict__ we, const float* __restrict__ pe,
                        float* __restrict__ X) {
  const int t = blockIdx.x;
  const int c = threadIdx.x;  // 0..319
  const int w = wt[t];
  const int p = pt[t];
  X[t * kE + c] = (c < 256) ? we[(size_t)w * 256 + c] : pe[p * 64 + (c - 256)];
}

// ---------------- generic f32 "NT" GEMM ----------------
template <int BM, int BN, int BK>
__global__ __launch_bounds__(256) void gemm_nt(
    const float* __restrict__ A, int lda,
    const float* __restrict__ B, int ldb,
    const float* __restrict__ b1, const float* __restrict__ b2, float scale,
    float* __restrict__ C, int csm, int csn, int K) {
  const int tid = threadIdx.x;
  const int m0 = blockIdx.y * BM;
  const int n0 = blockIdx.x * BN;
  __shared__ float As[BK][BM];
  __shared__ float Bs[BK][BN];
  const int lm = tid >> 2;
  const int lk = tid & 3;
  const int tx = tid & 15;
  const int ty = tid >> 4;
  float acc[4][4] = {};
  for (int k0 = 0; k0 < K; k0 += BK) {
    const float4 av = *(const float4*)(A + (size_t)(m0 + lm) * lda + k0 + lk * 4);
    const float4 bv = *(const float4*)(B + (size_t)(n0 + lm) * ldb + k0 + lk * 4);
    __syncthreads();
    As[lk * 4 + 0][lm] = av.x; As[lk * 4 + 1][lm] = av.y;
    As[lk * 4 + 2][lm] = av.z; As[lk * 4 + 3][lm] = av.w;
    Bs[lk * 4 + 0][lm] = bv.x; Bs[lk * 4 + 1][lm] = bv.y;
    Bs[lk * 4 + 2][lm] = bv.z; Bs[lk * 4 + 3][lm] = bv.w;
    __syncthreads();
#pragma unroll
    for (int kk = 0; kk < BK; ++kk) {
      const float4 a = *(const float4*)&As[kk][ty * 4];
      const float4 b = *(const float4*)&Bs[kk][tx * 4];
      acc[0][0] = fmaf(a.x, b.x, acc[0][0]);
      acc[0][1] = fmaf(a.x, b.y, acc[0][1]);
      acc[0][2] = fmaf(a.x, b.z, acc[0][2]);
      acc[0][3] = fmaf(a.x, b.w, acc[0][3]);
      acc[1][0] = fmaf(a.y, b.x, acc[1][0]);
      acc[1][1] = fmaf(a.y, b.y, acc[1][1]);
      acc[1][2] = fmaf(a.y, b.z, acc[1][2]);
      acc[1][3] = fmaf(a.y, b.w, acc[1][3]);
      acc[2][0] = fmaf(a.z, b.x, acc[2][0]);
      acc[2][1] = fmaf(a.z, b.y, acc[2][1]);
      acc[2][2] = fmaf(a.z, b.z, acc[2][2]);
      acc[2][3] = fmaf(a.z, b.w, acc[2][3]);
      acc[3][0] = fmaf(a.w, b.x, acc[3][0]);
      acc[3][1] = fmaf(a.w, b.y, acc[3][1]);
      acc[3][2] = fmaf(a.w, b.z, acc[3][2]);
      acc[3][3] = fmaf(a.w, b.w, acc[3][3]);
    }
  }
#pragma unroll
  for (int ii = 0; ii < 4; ++ii) {
#pragma unroll
    for (int jj = 0; jj < 4; ++jj) {
      const int m = m0 + ty * 4 + ii;
      const int n = n0 + tx * 4 + jj;
      float v = acc[ii][jj];
      if (b1) v += b1[n];
      if (b2) v += b2[n];
      C[(size_t)m * csm + (size_t)n * csn] = v * scale;
    }
  }
}

// ---------------- single-block-per-direction LSTM scan, f16, 2 rows/thread ----------------
// 2 blocks (d = blockIdx.x), 512 threads = 8 waves = EXACTLY 2 waves/EU.
// amdgpu_waves_per_eu(2,2) pins the allocator: 256-VGPR cap, no occupancy
// incentive to spill. Thread t owns gate rows {t, t+512}: cols 0..191 of both
// rows as 192 packed-f16 uints in VGPRs, cols 192..255 in LDS (128 KB).
// h broadcast as packed half2 from LDS (uniform addr). f32 accumulate via
// v_dot2_f32_f16. No inter-block communication.
__global__ __launch_bounds__(512)
__attribute__((amdgpu_waves_per_eu(2, 2)))
void lstm_scan_f16(
    const float* __restrict__ pre,   // (2, kSeq, kG) pregates
    const float* __restrict__ whh,   // (2, kG, kH) f32
    float* __restrict__ out) {       // (kSeq, kLH); dir d -> cols [d*kH, d*kH+kH)
  extern __shared__ __align__(16) char smem[];
  uint4*        wl4  = (uint4*)smem;                           // 8*1024 uint4 = 128KB
  float*        gbuf = (float*)(smem + 131072);                // 1024 f32 = 4KB
  unsigned int* hh   = (unsigned int*)(smem + 131072 + 4096);  // 128 uints = 512B

  const int d = blockIdx.x;
  const int t = threadIdx.x;   // 0..511; owns gate rows t and t+512

  // ---- prologue: convert both rows' weights to f16 ----
  unsigned int wreg[192];      // [0..95] row t cols 0..191, [96..191] row t+512
  {
    const float4* wp0 = (const float4*)(whh + ((size_t)d * kG + t) * kH);
    const float4* wp1 = (const float4*)(whh + ((size_t)d * kG + t + 512) * kH);
#pragma unroll
    for (int k = 0; k < 48; ++k) {
      const float4 v = wp0[k];
      wreg[2 * k]     = packh2(v.x, v.y);
      wreg[2 * k + 1] = packh2(v.z, v.w);
    }
#pragma unroll
    for (int k = 0; k < 48; ++k) {
      const float4 v = wp1[k];
      wreg[96 + 2 * k]     = packh2(v.x, v.y);
      wreg[96 + 2 * k + 1] = packh2(v.z, v.w);
    }
#pragma unroll
    for (int k = 0; k < 8; ++k) {   // cols 192..255 -> LDS, both rows
      float4 a = wp0[48 + 2 * k];
      float4 b = wp0[48 + 2 * k + 1];
      uint4 q;
      q.x = packh2(a.x, a.y); q.y = packh2(a.z, a.w);
      q.z = packh2(b.x, b.y); q.w = packh2(b.z, b.w);
      wl4[k * 1024 + t] = q;
      a = wp1[48 + 2 * k];
      b = wp1[48 + 2 * k + 1];
      q.x = packh2(a.x, a.y); q.y = packh2(a.z, a.w);
      q.z = packh2(b.x, b.y); q.w = packh2(b.z, b.w);
      wl4[k * 1024 + t + 512] = q;
    }
  }
  if (t < 128) hh[t] = 0u;     // h(-1) = 0
  __syncthreads();

  float c = 0.0f;
  const uint4* hh4 = (const uint4*)hh;   // 32 chunks of 4 half2 (8 cols each)

  for (int u = 0; u < kSeq; ++u) {
    const int ts = d ? (kSeq - 1 - u) : u;
    // issue pregate loads early; resolve under the dot
    const float* pp = pre + ((size_t)d * kSeq + ts) * kG;
    const float pg0 = pp[t];
    const float pg1 = pp[t + 512];

    float A0 = 0.f, A1 = 0.f, A2 = 0.f, A3 = 0.f;   // row t
    float B0 = 0.f, B1 = 0.f, B2 = 0.f, B3 = 0.f;   // row t+512
#pragma unroll
    for (int k = 0; k < 24; ++k) {       // cols 0..191 from VGPR weights
      const uint4 hv = hh4[k];           // broadcast LDS read (uniform addr)
      A0 = fdot2(wreg[4 * k + 0], hv.x, A0);
      A1 = fdot2(wreg[4 * k + 1], hv.y, A1);
      A2 = fdot2(wreg[4 * k + 2], hv.z, A2);
      A3 = fdot2(wreg[4 * k + 3], hv.w, A3);
      B0 = fdot2(wreg[96 + 4 * k + 0], hv.x, B0);
      B1 = fdot2(wreg[96 + 4 * k + 1], hv.y, B1);
      B2 = fdot2(wreg[96 + 4 * k + 2], hv.z, B2);
      B3 = fdot2(wreg[96 + 4 * k + 3], hv.w, B3);
    }
#pragma unroll
    for (int k = 0; k < 8; ++k) {        // cols 192..255 from LDS weights
      const uint4 hv = hh4[24 + k];
      const uint4 w0 = wl4[k * 1024 + t];
      const uint4 w1 = wl4[k * 1024 + t + 512];
      A0 = fdot2(w0.x, hv.x, A0);
      A1 = fdot2(w0.y, hv.y, A1);
      A2 = fdot2(w0.z, hv.z, A2);
      A3 = fdot2(w0.w, hv.w, A3);
      B0 = fdot2(w1.x, hv.x, B0);
      B1 = fdot2(w1.y, hv.y, B1);
      B2 = fdot2(w1.z, hv.z, B2);
      B3 = fdot2(w1.w, hv.w, B3);
    }
    gbuf[t]       = (A0 + A1) + (A2 + A3) + pg0;
    gbuf[t + 512] = (B0 + B1) + (B2 + B3) + pg1;
    __syncthreads();   // S1: all 1024 gates ready

    if (t < kH) {
      const float gi = gbuf[t];
      const float gf = gbuf[kH + t];
      const float gg = gbuf[2 * kH + t];
      const float go = gbuf[3 * kH + t];
      const float iv = sigm(gi), fv = sigm(gf);
      const float gv = tanh_(gg), ov = sigm(go);
      c = fv * c + iv * gv;
      const float h = ov * tanh_(c);
      ((_Float16*)hh)[t] = (_Float16)h;        // quantized h for the recurrence
      out[(size_t)ts * kLH + d * kH + t] = h;  // full-precision h downstream
    }
    __syncthreads();   // S2: hh(u) assembled
  }
}

// ---------------- pair scorer ----------------
__global__ __launch_bounds__(512) void score_k(
    const float* __restrict__ Up, const float* __restrict__ VT,
    const float* __restrict__ wout, const float* __restrict__ bout,
    float* __restrict__ out) {
  const int i = blockIdx.x;
  const int j = threadIdx.x;
  __shared__ float u_sh[kMLP];
  __shared__ float w_sh[kMLP];
  u_sh[j] = Up[(size_t)i * kMLP + j];
  w_sh[j] = wout[j];
  __syncthreads();
  float acc = 0.0f;
#pragma unroll 4
  for (int m = 0; m < kMLP; ++m) {
    const float x = u_sh[m] + VT[(size_t)m * kSeq + j];  // pre-scaled by 2*log2e
    const float th = 1.0f - 2.0f * frcpf(1.0f + fexp2f(x));
    acc = fmaf(th, w_sh[m], acc);
  }
  const float s = acc + bout[0];
  out[(size_t)i * kSeq + j] = (j == i) ? 0.0f : s;
}

extern "C" void kernel_launch(void* const* d_in, const int* in_sizes, int n_in,
                              void* d_out, int out_size, void* d_ws, size_t ws_size,
                              hipStream_t stream) {
  const int*   wt   = (const int*)d_in[0];
  const int*   pt   = (const int*)d_in[1];
  const float* wemb = (const float*)d_in[2];
  const float* pemb = (const float*)d_in[3];
  const float* wih0 = (const float*)d_in[4];
  const float* whh0 = (const float*)d_in[5];
  const float* bih0 = (const float*)d_in[6];
  const float* bhh0 = (const float*)d_in[7];
  const float* wih1 = (const float*)d_in[8];
  const float* whh1 = (const float*)d_in[9];
  const float* bih1 = (const float*)d_in[10];
  const float* bhh1 = (const float*)d_in[11];
  const float* wlin = (const float*)d_in[12];
  const float* blin = (const float*)d_in[13];
  const float* wout = (const float*)d_in[14];
  const float* bout = (const float*)d_in[15];
  float* outp = (float*)d_out;

  float* ws   = (float*)d_ws;
  float* X    = ws;                      // 512*320
  float* PG0  = X + kSeq * kE;           // 2*512*1024
  float* X1   = PG0 + 2 * kSeq * kG;     // 512*512
  float* PG1  = X1 + kSeq * kLH;         // 2*512*1024
  float* LOUT = PG1 + 2 * kSeq * kG;     // 512*512
  float* U    = LOUT + kSeq * kLH;       // 512*512
  float* VT   = U + kSeq * kMLP;         // 512*512

  const float SC = 2.8853900817779268f;  // 2*log2(e), folds tanh scaling
  const int kScanLds = 131072 + 4096 + 512;  // weights + gbuf + hh

  hipFuncSetAttribute(reinterpret_cast<const void*>(lstm_scan_f16),
                      hipFuncAttributeMaxDynamicSharedMemorySize, kScanLds);

  embed_k<<<kSeq, kE, 0, stream>>>(wt, pt, wemb, pemb, X);

  for (int d = 0; d < 2; ++d) {
    gemm_nt<64, 64, 16><<<dim3(kG / 64, kSeq / 64), 256, 0, stream>>>(
        X, kE, wih0 + (size_t)d * kG * kE, kE,
        bih0 + d * kG, bhh0 + d * kG, 1.0f,
        PG0 + (size_t)d * kSeq * kG, kG, 1, kE);
  }
  lstm_scan_f16<<<2, 512, kScanLds, stream>>>(PG0, whh0, X1);

  for (int d = 0; d < 2; ++d) {
    gemm_nt<64, 64, 16><<<dim3(kG / 64, kSeq / 64), 256, 0, stream>>>(
        X1, kLH, wih1 + (size_t)d * kG * kLH, kLH,
        bih1 + d * kG, bhh1 + d * kG, 1.0f,
        PG1 + (size_t)d * kSeq * kG, kG, 1, kLH);
  }
  lstm_scan_f16<<<2, 512, kScanLds, stream>>>(PG1, whh1, LOUT);

  gemm_nt<64, 64, 16><<<dim3(kMLP / 64, kSeq / 64), 256, 0, stream>>>(
      LOUT, kLH, wlin, 2 * kLH, nullptr, nullptr, SC,
      U, kMLP, 1, kLH);
  gemm_nt<64, 64, 16><<<dim3(kMLP / 64, kSeq / 64), 256, 0, stream>>>(
      LOUT, kLH, wlin + kLH, 2 * kLH, blin, nullptr, SC,
      VT, 1, kSeq, kLH);

  score_k<<<kSeq, 512, 0, stream>>>(U, VT, wout, bout, outp);
}